// Round 2
// baseline (275.736 us; speedup 1.0000x reference)
//
#include <hip/hip_runtime.h>
#include <hip/hip_fp16.h>

#define LOG2E 1.44269504088896340736f
#define DM 1536
#define LL  2048
#define NN  16
#define NCH 256    // chunks per row (4 waves x 64 lanes)
#define CL  8      // steps per chunk = LL / NCH

__device__ __forceinline__ float fexp2(float v){ return __builtin_amdgcn_exp2f(v); }
__device__ __forceinline__ float frcp(float v){ return __builtin_amdgcn_rcpf(v); }

__device__ __forceinline__ float packdx(float d, float x){
    return __builtin_bit_cast(float, __floats2half2_rn(d, x));   // d in low, x in high
}
__device__ __forceinline__ void unpackdx(float f, float& d, float& x){
    const float2 p = __half22float2(__builtin_bit_cast(__half2, f));
    d = p.x; x = p.y;
}
// float4 = 8 packed halfs -> 8 floats (v_cvt_f32_f16 with hi-sel, no shifts)
__device__ __forceinline__ void unpack8(const float4 f, float* o){
    float2 p;
    p = __half22float2(__builtin_bit_cast(__half2, f.x)); o[0]=p.x; o[1]=p.y;
    p = __half22float2(__builtin_bit_cast(__half2, f.y)); o[2]=p.x; o[3]=p.y;
    p = __half22float2(__builtin_bit_cast(__half2, f.z)); o[4]=p.x; o[5]=p.y;
    p = __half22float2(__builtin_bit_cast(__half2, f.w)); o[6]=p.x; o[7]=p.y;
}

// B,C fp32 [b][n][t] -> fp16 records: BC[((b*8 + (t&7))*256 + (t>>3))*32 + n]
// (B at +n, C at +16+n). Per (step r, chunk c) one contiguous 64 B record;
// per r the 256 chunks form one 16 KB slab read coalesced by 4 waves.
__global__ __launch_bounds__(256) void transpose_bc(
        const float* __restrict__ Bm, const float* __restrict__ Cm,
        __half* __restrict__ BC){
    const int q  = blockIdx.x*256 + threadIdx.x;   // 16384 float4 quads
    const int t0 = (q & 511) << 2;
    const int n  = (q >> 9) & 15;
    const int b  = q >> 13;
    const long i = (long)(b*NN + n)*LL + t0;
    const float4 bv = *(const float4*)(Bm + i);
    const float4 cv = *(const float4*)(Cm + i);
    const float bb[4]={bv.x,bv.y,bv.z,bv.w}, cc[4]={cv.x,cv.y,cv.z,cv.w};
#pragma unroll
    for (int j=0;j<4;++j){
        const int t = t0 + j;
        const long o = ((long)((b*CL + (t&7))*NCH + (t>>3)))*32 + n;
        BC[o]      = __float2half_rn(bb[j]);
        BC[o + 16] = __float2half_rn(cc[j]);
    }
}

// Block = 4 waves = ONE row-pair (2 consecutive d, same b). 256 chunks x 8
// steps; wave w owns chunks [w*64, w*64+64), lane = chunk within wave.
// Thread carries 16 states x 2 rows. Two-level scan: Kogge-Stone within each
// wave, all wave totals -> LDS -> one __syncthreads -> wave w composes the
// prefix of waves 0..w-1 serially (<=3 fma-composes per n), then
// h_start = fma(P_excl, G_wave_prefix, G_excl). BC traffic unchanged vs the
// 2-wave version (2 rows share each record read) but waves/CU go 12 -> 24.
// LDS 17 KB. delta/x packed half2 at slot(r,c) = r*256 + c (all accesses are
// 512 B contiguous per wave -> bandwidth-bound, no conflicts, no swizzle);
// phase 3 overwrites the slot with fp32 {y0,y1} (same-wave only, no barrier).
__global__ __launch_bounds__(256, 6) void ssm_scan(
    const float* __restrict__ x, const float* __restrict__ delta,
    const float* __restrict__ A, const float* __restrict__ Dv,
    const float* __restrict__ z, const __half* __restrict__ BC,
    float* __restrict__ out)
{
    __shared__ float2 sdx[CL*NCH];     // 16 KB
    __shared__ float  wtP[4][2][NN];   // per-wave inclusive totals
    __shared__ float  wtG[4][2][NN];

    const int lane = threadIdx.x & 63;
    const int w    = threadIdx.x >> 6;
    const int cmy  = threadIdx.x;            // my chunk (0..255)
    const int row0 = blockIdx.x*2;           // b*DM + d ; row1 = row0+1
    const int b    = (row0 >= DM) ? 1 : 0;
    const int d0   = row0 - b*DM;

    const long base0 = (long)row0*LL;
    const long base1 = base0 + LL;
    const float* gd0 = delta + base0; const float* gx0 = x + base0;
    const float* gd1 = delta + base1; const float* gx1 = x + base1;

    // ---- stage packed (d,x) for both rows; wave w covers t in [w*512, +512)
    for (int k=0;k<512;k+=256){
        const int t0 = w*512 + k + lane*4;
        const float4 dv0 = *(const float4*)(gd0 + t0);
        const float4 xv0 = *(const float4*)(gx0 + t0);
        const float4 dv1 = *(const float4*)(gd1 + t0);
        const float4 xv1 = *(const float4*)(gx1 + t0);
        const float dd0[4]={dv0.x,dv0.y,dv0.z,dv0.w}, xx0[4]={xv0.x,xv0.y,xv0.z,xv0.w};
        const float dd1[4]={dv1.x,dv1.y,dv1.z,dv1.w}, xx1[4]={xv1.x,xv1.y,xv1.z,xv1.w};
#pragma unroll
        for (int j=0;j<4;++j){
            const int t = t0 + j, r = t & 7, c = t >> 3;
            float2 wd; wd.x = packdx(dd0[j], xx0[j]); wd.y = packdx(dd1[j], xx1[j]);
            sdx[r*NCH + c] = wd;
        }
    }

    float A20[NN], A21[NN];
#pragma unroll
    for (int n=0;n<NN;++n){
        A20[n] = A[d0*NN+n]     * LOG2E;
        A21[n] = A[(d0+1)*NN+n] * LOG2E;
    }

    // record for (b, r, chunk cmy): BC + b*65536 + r*8192 + cmy*32 (halfs)
    const __half* bc = BC + (long)b*65536 + cmy*32;

    // ---- phase 1: local chunk scan h0=0 -> G (both rows); dsum -> P
    float G0[NN], G1[NN];
#pragma unroll
    for (int n=0;n<NN;++n){ G0[n]=0.f; G1[n]=0.f; }
    float ds0=0.f, ds1=0.f;
#pragma unroll 2
    for (int r=0;r<CL;++r){
        const float2 wd = sdx[r*NCH + cmy];
        const float4* rec = (const float4*)(bc + (long)r*8192);
        float bb[16];
        unpack8(rec[0], bb); unpack8(rec[1], bb+8);
        float d_0,x_0,d_1,x_1;
        unpackdx(wd.x, d_0, x_0); unpackdx(wd.y, d_1, x_1);
        ds0 += d_0; ds1 += d_1;
        const float dx0 = d_0*x_0, dx1 = d_1*x_1;
#pragma unroll
        for (int n=0;n<NN;++n){
            const float e0 = fexp2(d_0*A20[n]);
            G0[n] = __builtin_fmaf(e0, G0[n], bb[n]*dx0);
            const float e1 = fexp2(d_1*A21[n]);
            G1[n] = __builtin_fmaf(e1, G1[n], bb[n]*dx1);
        }
    }

    // ---- phase 2: two-level scan (KS within wave, serial compose across 4 waves)
    float h0[NN], h1[NN];
    {
        float P0[NN], P1[NN];
#pragma unroll
        for (int n=0;n<NN;++n){ P0[n]=fexp2(ds0*A20[n]); P1[n]=fexp2(ds1*A21[n]); }
        // inclusive Kogge-Stone within wave
#pragma unroll
        for (int s=1;s<64;s<<=1){
#pragma unroll
            for (int n=0;n<NN;++n){
                const float pl0=__shfl_up(P0[n],s), gl0=__shfl_up(G0[n],s);
                const float pl1=__shfl_up(P1[n],s), gl1=__shfl_up(G1[n],s);
                if (lane >= s){
                    G0[n]=__builtin_fmaf(P0[n],gl0,G0[n]); P0[n]*=pl0;
                    G1[n]=__builtin_fmaf(P1[n],gl1,G1[n]); P1[n]*=pl1;
                }
            }
        }
        // every wave publishes its inclusive total
        if (lane==63){
#pragma unroll
            for (int n=0;n<NN;++n){
                wtP[w][0][n]=P0[n]; wtG[w][0][n]=G0[n];
                wtP[w][1][n]=P1[n]; wtG[w][1][n]=G1[n];
            }
        }
        __syncthreads();
        // exclusive within wave, then compose with prefix of preceding waves
#pragma unroll
        for (int n=0;n<NN;++n){
            const float pe0=__shfl_up(P0[n],1), ge0=__shfl_up(G0[n],1);
            const float pe1=__shfl_up(P1[n],1), ge1=__shfl_up(G1[n],1);
            const float Px0 = (lane==0)?1.f:pe0, Gx0 = (lane==0)?0.f:ge0;
            const float Px1 = (lane==0)?1.f:pe1, Gx1 = (lane==0)?0.f:ge1;
            float gp0 = 0.f, gp1 = 0.f;
            for (int wv=0; wv<w; ++wv){          // wave-uniform trip count
                gp0 = __builtin_fmaf(wtP[wv][0][n], gp0, wtG[wv][0][n]);
                gp1 = __builtin_fmaf(wtP[wv][1][n], gp1, wtG[wv][1][n]);
            }
            h0[n] = __builtin_fmaf(Px0, gp0, Gx0);
            h1[n] = __builtin_fmaf(Px1, gp1, Gx1);
        }
    }

    // ---- phase 3: re-scan with true h_start; stash fp32 {y0+x0*D0, y1+x1*D1}
    const float Dd0 = Dv[d0], Dd1 = Dv[d0+1];
#pragma unroll 2
    for (int r=0;r<CL;++r){
        const int slot = r*NCH + cmy;
        const float2 wd = sdx[slot];
        const float4* rec = (const float4*)(bc + (long)r*8192);
        float bb[16], cc[16];
        unpack8(rec[0], bb); unpack8(rec[1], bb+8);
        unpack8(rec[2], cc); unpack8(rec[3], cc+8);
        float d_0,x_0,d_1,x_1;
        unpackdx(wd.x, d_0, x_0); unpackdx(wd.y, d_1, x_1);
        const float dx0 = d_0*x_0, dx1 = d_1*x_1;
        float ya0=0.f, yb0=0.f, ya1=0.f, yb1=0.f;
#pragma unroll
        for (int n=0;n<NN;n+=2){
            const float e0a = fexp2(d_0*A20[n]);
            h0[n]  =__builtin_fmaf(e0a,h0[n],  bb[n]*dx0);   ya0=__builtin_fmaf(h0[n],  cc[n],  ya0);
            const float e0b = fexp2(d_0*A20[n+1]);
            h0[n+1]=__builtin_fmaf(e0b,h0[n+1],bb[n+1]*dx0); yb0=__builtin_fmaf(h0[n+1],cc[n+1],yb0);
            const float e1a = fexp2(d_1*A21[n]);
            h1[n]  =__builtin_fmaf(e1a,h1[n],  bb[n]*dx1);   ya1=__builtin_fmaf(h1[n],  cc[n],  ya1);
            const float e1b = fexp2(d_1*A21[n+1]);
            h1[n+1]=__builtin_fmaf(e1b,h1[n+1],bb[n+1]*dx1); yb1=__builtin_fmaf(h1[n+1],cc[n+1],yb1);
        }
        float2 yo;
        yo.x = __builtin_fmaf(x_0, Dd0, ya0+yb0);
        yo.y = __builtin_fmaf(x_1, Dd1, ya1+yb1);
        sdx[slot] = yo;                        // silu applied in epilogue
    }

    // ---- epilogue: stream z once per row, coalesced float4 in/out
    // wave w reads t in [w*512, +512) -> chunks [w*64, +64): same-wave slots only
    const float* gz0 = z + base0; const float* gz1 = z + base1;
    float* go0 = out + base0;     float* go1 = out + base1;
    for (int k=0;k<512;k+=256){
        const int t0 = w*512 + k + lane*4;
        const float4 zv0 = *(const float4*)(gz0 + t0);
        const float4 zv1 = *(const float4*)(gz1 + t0);
        const float zz0[4]={zv0.x,zv0.y,zv0.z,zv0.w}, zz1[4]={zv1.x,zv1.y,zv1.z,zv1.w};
        float o0[4], o1[4];
#pragma unroll
        for (int j=0;j<4;++j){
            const int t = t0 + j, r = t & 7, c = t >> 3;
            const float2 wd = sdx[r*NCH + c];
            const float s0 = frcp(1.f + fexp2(-zz0[j]*LOG2E));
            const float s1 = frcp(1.f + fexp2(-zz1[j]*LOG2E));
            o0[j] = wd.x * (zz0[j]*s0);
            o1[j] = wd.y * (zz1[j]*s1);
        }
        float4 a  = {o0[0],o0[1],o0[2],o0[3]};
        float4 bq = {o1[0],o1[1],o1[2],o1[3]};
        *(float4*)(go0 + t0) = a;
        *(float4*)(go1 + t0) = bq;
    }
}

extern "C" void kernel_launch(void* const* d_in, const int* in_sizes, int n_in,
                              void* d_out, int out_size, void* d_ws, size_t ws_size,
                              hipStream_t stream) {
    const float* x     = (const float*)d_in[0];
    const float* delta = (const float*)d_in[1];
    const float* A     = (const float*)d_in[2];
    const float* B     = (const float*)d_in[3];
    const float* C     = (const float*)d_in[4];
    const float* Dv    = (const float*)d_in[5];
    const float* z     = (const float*)d_in[6];
    float* out = (float*)d_out;

    __half* BC = (__half*)d_ws;               // 131072 halfs = 256 KB

    transpose_bc<<<dim3(64), dim3(256), 0, stream>>>(B, C, BC);
    ssm_scan<<<dim3(DM), dim3(256), 0, stream>>>(x, delta, A, Dv, z, BC, out);
}

// Round 3
// 181.638 us; speedup vs baseline: 1.5181x; 1.5181x over previous
//
#include <hip/hip_runtime.h>
#include <hip/hip_fp16.h>

#define LOG2E 1.44269504088896340736f
#define DM 1536
#define LL  2048
#define NN  16
#define NCH 256    // chunks per row (4 waves x 64 lanes)
#define CL  8      // steps per chunk = LL / NCH

__device__ __forceinline__ float fexp2(float v){ return __builtin_amdgcn_exp2f(v); }
__device__ __forceinline__ float frcp(float v){ return __builtin_amdgcn_rcpf(v); }

__device__ __forceinline__ float packdx(float d, float x){
    return __builtin_bit_cast(float, __floats2half2_rn(d, x));   // d in low, x in high
}
__device__ __forceinline__ void unpackdx(float f, float& d, float& x){
    const float2 p = __half22float2(__builtin_bit_cast(__half2, f));
    d = p.x; x = p.y;
}
// float4 = 8 packed halfs -> 8 floats (v_cvt_f32_f16 with hi-sel, no shifts)
__device__ __forceinline__ void unpack8(const float4 f, float* o){
    float2 p;
    p = __half22float2(__builtin_bit_cast(__half2, f.x)); o[0]=p.x; o[1]=p.y;
    p = __half22float2(__builtin_bit_cast(__half2, f.y)); o[2]=p.x; o[3]=p.y;
    p = __half22float2(__builtin_bit_cast(__half2, f.z)); o[4]=p.x; o[5]=p.y;
    p = __half22float2(__builtin_bit_cast(__half2, f.w)); o[6]=p.x; o[7]=p.y;
}

// B,C fp32 [b][n][t] -> fp16 records: BC[((b*8 + (t&7))*256 + (t>>3))*32 + n]
// (B at +n, C at +16+n). Per (step r, chunk c) one contiguous 64 B record;
// per r the 256 chunks form one 16 KB slab read coalesced by 4 waves.
__global__ __launch_bounds__(256) void transpose_bc(
        const float* __restrict__ Bm, const float* __restrict__ Cm,
        __half* __restrict__ BC){
    const int q  = blockIdx.x*256 + threadIdx.x;   // 16384 float4 quads
    const int t0 = (q & 511) << 2;
    const int n  = (q >> 9) & 15;
    const int b  = q >> 13;
    const long i = (long)(b*NN + n)*LL + t0;
    const float4 bv = *(const float4*)(Bm + i);
    const float4 cv = *(const float4*)(Cm + i);
    const float bb[4]={bv.x,bv.y,bv.z,bv.w}, cc[4]={cv.x,cv.y,cv.z,cv.w};
#pragma unroll
    for (int j=0;j<4;++j){
        const int t = t0 + j;
        const long o = ((long)((b*CL + (t&7))*NCH + (t>>3)))*32 + n;
        BC[o]      = __float2half_rn(bb[j]);
        BC[o + 16] = __float2half_rn(cc[j]);
    }
}

// Block = 4 waves = ONE row (one d of one b). 256 chunks x 8 steps; wave w
// owns chunks [w*64, w*64+64), lane = chunk within wave. Thread carries 16
// states x 1 row (~80 VGPR live in phase 3 -> NO spill, unlike the 2-row
// variant which needed ~100 and spilled 520 MB of scratch under a 6-wave cap).
// Grid = 2*DM = 3072 blocks = 12288 waves; occupancy is VGPR-limited at
// ~6 waves/SIMD = 24 waves/CU (2x round-0). Two-level scan: Kogge-Stone
// within each wave, wave totals -> LDS -> one __syncthreads -> wave w
// composes prefix of waves 0..w-1 serially. BC records are re-read by 2x
// more blocks than the pair scheme, but BC = 256 KB is L2-resident, so the
// extra ~300 MB is L2 traffic (~15 TB/s demand vs 34.5 achievable), not HBM.
// LDS 8.5 KB. delta/x packed half2 at slot(r,c) = r*256 + c; all LDS accesses
// are wave-contiguous (<=2 lanes/bank = free); phase 3 overwrites the slot
// with fp32 y (same-wave only, no barrier needed).
__global__ __launch_bounds__(256, 4) void ssm_scan(
    const float* __restrict__ x, const float* __restrict__ delta,
    const float* __restrict__ A, const float* __restrict__ Dv,
    const float* __restrict__ z, const __half* __restrict__ BC,
    float* __restrict__ out)
{
    __shared__ float sdx[CL*NCH];      // 8 KB
    __shared__ float wtP[4][NN];       // per-wave inclusive totals
    __shared__ float wtG[4][NN];

    const int lane = threadIdx.x & 63;
    const int w    = threadIdx.x >> 6;
    const int cmy  = threadIdx.x;            // my chunk (0..255)
    const int row  = blockIdx.x;             // = b*DM + d
    const int b    = (row >= DM) ? 1 : 0;
    const int d0   = row - b*DM;

    const long base = (long)row*LL;
    const float* gd = delta + base; const float* gx = x + base;

    // ---- stage packed (d,x); wave w covers t in [w*512, +512) = its own chunks
    for (int k=0;k<512;k+=256){
        const int t0 = w*512 + k + lane*4;
        const float4 dv = *(const float4*)(gd + t0);
        const float4 xv = *(const float4*)(gx + t0);
        const float dd[4]={dv.x,dv.y,dv.z,dv.w}, xx[4]={xv.x,xv.y,xv.z,xv.w};
#pragma unroll
        for (int j=0;j<4;++j){
            const int t = t0 + j, r = t & 7, c = t >> 3;
            sdx[r*NCH + c] = packdx(dd[j], xx[j]);
        }
    }

    float A2[NN];
#pragma unroll
    for (int n=0;n<NN;++n) A2[n] = A[d0*NN+n] * LOG2E;

    // record for (b, r, chunk cmy): BC + b*65536 + r*8192 + cmy*32 (halfs)
    const __half* bc = BC + (long)b*65536 + cmy*32;

    // ---- phase 1: local chunk scan h0=0 -> G; dsum -> P
    float G[NN];
#pragma unroll
    for (int n=0;n<NN;++n) G[n]=0.f;
    float ds=0.f;
#pragma unroll 2
    for (int r=0;r<CL;++r){
        const float wd = sdx[r*NCH + cmy];
        const float4* rec = (const float4*)(bc + (long)r*8192);
        float bb[16];
        unpack8(rec[0], bb); unpack8(rec[1], bb+8);
        float d_, x_;
        unpackdx(wd, d_, x_);
        ds += d_;
        const float dx = d_*x_;
#pragma unroll
        for (int n=0;n<NN;++n){
            const float e = fexp2(d_*A2[n]);
            G[n] = __builtin_fmaf(e, G[n], bb[n]*dx);
        }
    }

    // ---- phase 2: two-level scan (KS within wave, serial compose across 4 waves)
    float h[NN];
    {
        float P[NN];
#pragma unroll
        for (int n=0;n<NN;++n) P[n]=fexp2(ds*A2[n]);
        // inclusive Kogge-Stone within wave
#pragma unroll
        for (int s=1;s<64;s<<=1){
#pragma unroll
            for (int n=0;n<NN;++n){
                const float pl=__shfl_up(P[n],s), gl=__shfl_up(G[n],s);
                if (lane >= s){
                    G[n]=__builtin_fmaf(P[n],gl,G[n]); P[n]*=pl;
                }
            }
        }
        // every wave publishes its inclusive total
        if (lane==63){
#pragma unroll
            for (int n=0;n<NN;++n){ wtP[w][n]=P[n]; wtG[w][n]=G[n]; }
        }
        __syncthreads();
        // exclusive within wave, then compose with prefix of preceding waves
#pragma unroll
        for (int n=0;n<NN;++n){
            const float pe=__shfl_up(P[n],1), ge=__shfl_up(G[n],1);
            const float Px = (lane==0)?1.f:pe, Gx = (lane==0)?0.f:ge;
            float gp = 0.f;
            for (int wv=0; wv<w; ++wv){          // wave-uniform trip count
                gp = __builtin_fmaf(wtP[wv][n], gp, wtG[wv][n]);
            }
            h[n] = __builtin_fmaf(Px, gp, Gx);
        }
    }

    // ---- phase 3: re-scan with true h_start; stash fp32 y + x*D in the slot
    const float Dd = Dv[d0];
#pragma unroll 2
    for (int r=0;r<CL;++r){
        const int slot = r*NCH + cmy;
        const float wd = sdx[slot];
        const float4* rec = (const float4*)(bc + (long)r*8192);
        float bb[16], cc[16];
        unpack8(rec[0], bb); unpack8(rec[1], bb+8);
        unpack8(rec[2], cc); unpack8(rec[3], cc+8);
        float d_, x_;
        unpackdx(wd, d_, x_);
        const float dx = d_*x_;
        float ya=0.f, yb=0.f;
#pragma unroll
        for (int n=0;n<NN;n+=2){
            const float ea = fexp2(d_*A2[n]);
            h[n]  =__builtin_fmaf(ea,h[n],  bb[n]*dx);   ya=__builtin_fmaf(h[n],  cc[n],  ya);
            const float eb = fexp2(d_*A2[n+1]);
            h[n+1]=__builtin_fmaf(eb,h[n+1],bb[n+1]*dx); yb=__builtin_fmaf(h[n+1],cc[n+1],yb);
        }
        sdx[slot] = __builtin_fmaf(x_, Dd, ya+yb);   // silu applied in epilogue
    }

    // ---- epilogue: stream z once, coalesced float4 in/out
    // wave w reads t in [w*512, +512) -> chunks [w*64, +64): same-wave slots only
    const float* gz = z + base;
    float* go = out + base;
    for (int k=0;k<512;k+=256){
        const int t0 = w*512 + k + lane*4;
        const float4 zv = *(const float4*)(gz + t0);
        const float zz[4]={zv.x,zv.y,zv.z,zv.w};
        float o[4];
#pragma unroll
        for (int j=0;j<4;++j){
            const int t = t0 + j, r = t & 7, c = t >> 3;
            const float yv = sdx[r*NCH + c];
            const float s = frcp(1.f + fexp2(-zz[j]*LOG2E));
            o[j] = yv * (zz[j]*s);
        }
        float4 a = {o[0],o[1],o[2],o[3]};
        *(float4*)(go + t0) = a;
    }
}

extern "C" void kernel_launch(void* const* d_in, const int* in_sizes, int n_in,
                              void* d_out, int out_size, void* d_ws, size_t ws_size,
                              hipStream_t stream) {
    const float* x     = (const float*)d_in[0];
    const float* delta = (const float*)d_in[1];
    const float* A     = (const float*)d_in[2];
    const float* B     = (const float*)d_in[3];
    const float* C     = (const float*)d_in[4];
    const float* Dv    = (const float*)d_in[5];
    const float* z     = (const float*)d_in[6];
    float* out = (float*)d_out;

    __half* BC = (__half*)d_ws;               // 131072 halfs = 256 KB

    transpose_bc<<<dim3(64), dim3(256), 0, stream>>>(B, C, BC);
    ssm_scan<<<dim3(2*DM), dim3(256), 0, stream>>>(x, delta, A, Dv, z, BC, out);
}